// Round 2
// baseline (327.926 us; speedup 1.0000x reference)
//
#include <hip/hip_runtime.h>
#include <math.h>

#define D_DIM 2048
#define T_DIM 128
#define TT 16   // t-values per block

// T1 swizzle: flips e' bit0 by e' bit5 (j0 on write side, r0 on read side)
__device__ __forceinline__ int sw1(int x) { return x ^ ((x >> 5) & 1); }
// T2/T3 swizzle: flips e' bit0 by e' bit4
__device__ __forceinline__ int sw2(int x) { return x ^ ((x >> 4) & 1); }

// radix-2 butterfly over register-index bit MM (fully unrolled, constant idx)
#define BFLY(MM)                                              \
    _Pragma("unroll")                                         \
    for (int i_ = 0; i_ < 64; ++i_) {                         \
        if ((i_ & (MM)) == 0) {                               \
            float a_ = v[i_], b_ = v[i_ | (MM)];              \
            v[i_] = a_ + b_;                                  \
            v[i_ | (MM)] = a_ - b_;                           \
        }                                                     \
    }

__global__ __launch_bounds__(512, 4)
void fwht_apply_kernel(const float* __restrict__ z,
                       const float* __restrict__ d1,
                       const float* __restrict__ d2,
                       const float* __restrict__ d3,
                       const float* __restrict__ bvec,
                       float* __restrict__ out) {
    __shared__ float lds[1024 * TT];            // 64 KiB = half-D transpose tile
    const int tid = threadIdx.x;
    const int r   = tid >> 4;                   // 5-bit "rest" coordinate (0..31)
    const int tt  = tid & 15;                   // t within tile (0..15)
    const int bid = blockIdx.x;
    const int km  = bid >> 3;                   // (k,m) slab (128 total)
    const int t0  = (bid & 7) << 4;             // t-tile base (8 tiles of 16)
    const float s = 0.022097086912079608f;      // 1/sqrt(2048), one per H

    const float* zb = z + ((size_t)km * D_DIM) * T_DIM + t0 + tt;
    float v[64];

    // ---- P1: e = (j<<5)|r.  Load * (d1*s); F1 on e-bits 5..10 ----
    // wave lanes per j: 4 r-rows x 16 consecutive t = 64B segments (no over-fetch)
    #pragma unroll
    for (int j = 0; j < 64; ++j) {
        const int e = (j << 5) | r;
        v[j] = zb[(size_t)e * T_DIM] * (d1[e] * s);
    }
    BFLY(1) BFLY(2) BFLY(4) BFLY(8) BFLY(16) BFLY(32)

    // ---- T1: partition e-bit10 (= j5 on both sides). e' = e & 1023 ----
    #pragma unroll
    for (int j = 0; j < 32; ++j)                      // round A write (e10=0)
        lds[sw1((j << 5) | r) * TT + tt] = v[j];
    __syncthreads();
    #pragma unroll
    for (int j = 0; j < 32; ++j)                      // round A read: P2 map
        v[j] = lds[sw1(j | (r << 5)) * TT + tt];
    __syncthreads();
    #pragma unroll
    for (int j = 32; j < 64; ++j)                     // round B write (e10=1)
        lds[sw1(((j & 31) << 5) | r) * TT + tt] = v[j];
    __syncthreads();
    #pragma unroll
    for (int j = 32; j < 64; ++j)                     // round B read
        v[j] = lds[sw1((j & 31) | (r << 5)) * TT + tt];
    __syncthreads();

    // ---- P2: e = (j&31) | ((j>>5)<<10) | (r<<5) ----
    BFLY(1) BFLY(2) BFLY(4) BFLY(8) BFLY(16)          // F1 e-bits 0..4 (F1 done)
    {   // * d2 * s : per-thread e is two contiguous runs of 32 -> float4
        const float4* q0 = (const float4*)(d2 + (r << 5));
        const float4* q1 = (const float4*)(d2 + 1024 + (r << 5));
        #pragma unroll
        for (int q = 0; q < 8; ++q) {
            float4 a = q0[q];
            v[4*q+0] *= a.x * s; v[4*q+1] *= a.y * s;
            v[4*q+2] *= a.z * s; v[4*q+3] *= a.w * s;
            float4 c = q1[q];
            v[32+4*q+0] *= c.x * s; v[32+4*q+1] *= c.y * s;
            v[32+4*q+2] *= c.z * s; v[32+4*q+3] *= c.w * s;
        }
    }
    BFLY(1) BFLY(2) BFLY(4) BFLY(8) BFLY(16) BFLY(32) // F2 e-bits 0..4,10

    // ---- T2: partition e-bit0 (= j0 on both sides). e' = e >> 1 ----
    // P2-side e' = ((j>>1)&15) | (r<<4) | ((j>>5)<<9)
    // P3-side e' = (((j>>1)&31)<<4) | (r&15) | ((r>>4)<<9)
    #pragma unroll
    for (int j = 0; j < 64; j += 2)                   // round A write (e0=0)
        lds[sw2(((j >> 1) & 15) | (r << 4) | ((j >> 5) << 9)) * TT + tt] = v[j];
    __syncthreads();
    #pragma unroll
    for (int j = 0; j < 64; j += 2)                   // round A read: P3 map
        v[j] = lds[sw2((((j >> 1) & 31) << 4) | (r & 15) | ((r >> 4) << 9)) * TT + tt];
    __syncthreads();
    #pragma unroll
    for (int j = 1; j < 64; j += 2)                   // round B write (e0=1)
        lds[sw2(((j >> 1) & 15) | (r << 4) | ((j >> 5) << 9)) * TT + tt] = v[j];
    __syncthreads();
    #pragma unroll
    for (int j = 1; j < 64; j += 2)                   // round B read
        v[j] = lds[sw2((((j >> 1) & 31) << 4) | (r & 15) | ((r >> 4) << 9)) * TT + tt];
    __syncthreads();

    // ---- P3: e = ((j>>1)<<5) | (j&1) | eRest, eRest = ((r&15)<<1)|((r>>4)<<10)
    //      register e-bits: j0<->e0, j1..j5<->e5..9 ----
    BFLY(2) BFLY(4) BFLY(8) BFLY(16) BFLY(32)         // F2 e-bits 5..9 (F2 done)
    {   // * d3 * s : (v[2m], v[2m+1]) sit at (e, e+1) -> float2
        const int eRest = ((r & 15) << 1) | ((r >> 4) << 10);
        #pragma unroll
        for (int m = 0; m < 32; ++m) {
            float2 a = *(const float2*)(d3 + ((m << 5) | eRest));
            v[2*m]   *= a.x * s;
            v[2*m+1] *= a.y * s;
        }
    }
    BFLY(2) BFLY(4) BFLY(8) BFLY(16) BFLY(32) BFLY(1) // F3 e-bits 5..9, 0

    // ---- T3: partition e-bit0 (= j0 on both sides). e' = e >> 1 ----
    // P3-side e' = (((j>>1)&31)<<4) | (r&15) | ((r>>4)<<9)
    // P4-side e' = ((j>>1)&15) | (r<<4) | ((j>>5)<<9)
    #pragma unroll
    for (int j = 0; j < 64; j += 2)                   // round A write (e0=0)
        lds[sw2((((j >> 1) & 31) << 4) | (r & 15) | ((r >> 4) << 9)) * TT + tt] = v[j];
    __syncthreads();
    #pragma unroll
    for (int j = 0; j < 64; j += 2)                   // round A read: P4(=P2) map
        v[j] = lds[sw2(((j >> 1) & 15) | (r << 4) | ((j >> 5) << 9)) * TT + tt];
    __syncthreads();
    #pragma unroll
    for (int j = 1; j < 64; j += 2)                   // round B write (e0=1)
        lds[sw2((((j >> 1) & 31) << 4) | (r & 15) | ((r >> 4) << 9)) * TT + tt] = v[j];
    __syncthreads();
    #pragma unroll
    for (int j = 1; j < 64; j += 2)                   // round B read
        v[j] = lds[sw2(((j >> 1) & 15) | (r << 4) | ((j >> 5) << 9)) * TT + tt];

    // ---- P4: e = (j&31) | ((j>>5)<<10) | (r<<5). F3 e-bits 1..4, 10 ----
    BFLY(2) BFLY(4) BFLY(8) BFLY(16) BFLY(32)         // F3 done

    float* ob = out + ((size_t)km * D_DIM) * T_DIM + t0 + tt;
    {   // + b, store.  b is two contiguous runs of 32 -> float4
        const float4* q0 = (const float4*)(bvec + (r << 5));
        const float4* q1 = (const float4*)(bvec + 1024 + (r << 5));
        #pragma unroll
        for (int q = 0; q < 8; ++q) {
            float4 a = q0[q];
            const int e0 = (r << 5) + 4*q;
            ob[(size_t)(e0+0) * T_DIM] = v[4*q+0] + a.x;
            ob[(size_t)(e0+1) * T_DIM] = v[4*q+1] + a.y;
            ob[(size_t)(e0+2) * T_DIM] = v[4*q+2] + a.z;
            ob[(size_t)(e0+3) * T_DIM] = v[4*q+3] + a.w;
            float4 c = q1[q];
            const int e1 = 1024 + (r << 5) + 4*q;
            ob[(size_t)(e1+0) * T_DIM] = v[32+4*q+0] + c.x;
            ob[(size_t)(e1+1) * T_DIM] = v[32+4*q+1] + c.y;
            ob[(size_t)(e1+2) * T_DIM] = v[32+4*q+2] + c.z;
            ob[(size_t)(e1+3) * T_DIM] = v[32+4*q+3] + c.w;
        }
    }
}

__global__ void sldj_kernel(const float* __restrict__ d1,
                            const float* __restrict__ d2,
                            const float* __restrict__ d3,
                            const float* __restrict__ sldj_in,
                            float* __restrict__ out) {
    __shared__ float red[256];
    const int tid = threadIdx.x;
    float acc = 0.0f;
    for (int i = tid; i < D_DIM; i += 256) {
        acc += logf(fabsf(d1[i])) + logf(fabsf(d2[i])) + logf(fabsf(d3[i]));
    }
    red[tid] = acc;
    __syncthreads();
    #pragma unroll
    for (int sft = 128; sft > 0; sft >>= 1) {
        if (tid < sft) red[tid] += red[tid + sft];
        __syncthreads();
    }
    const float tot = red[0];
    if (tid < 128) out[tid] = sldj_in[tid] + tot;
}

extern "C" void kernel_launch(void* const* d_in, const int* in_sizes, int n_in,
                              void* d_out, int out_size, void* d_ws, size_t ws_size,
                              hipStream_t stream) {
    const float* z    = (const float*)d_in[0];
    const float* d1   = (const float*)d_in[1];
    const float* d2   = (const float*)d_in[2];
    const float* d3   = (const float*)d_in[3];
    const float* bvec = (const float*)d_in[4];
    const float* sldj = (const float*)d_in[5];
    float* out = (float*)d_out;

    // K*M = 128 slabs, 8 t-tiles of 16 -> 1024 blocks of 512 threads
    fwht_apply_kernel<<<1024, 512, 0, stream>>>(z, d1, d2, d3, bvec, out);
    sldj_kernel<<<1, 256, 0, stream>>>(d1, d2, d3, sldj,
                                       out + (size_t)4 * 32 * 2048 * 128);
}

// Round 3
// 302.406 us; speedup vs baseline: 1.0844x; 1.0844x over previous
//
#include <hip/hip_runtime.h>
#include <math.h>

#define D_DIM 2048
#define T_DIM 128
#define TT 16   // t-values per block

// T1 swizzle: flips e' bit0 by e' bit5 (j0 on write side, r0 on read side)
__device__ __forceinline__ int sw1(int x) { return x ^ ((x >> 5) & 1); }
// T2/T3 swizzle: flips e' bit0 by e' bit4
__device__ __forceinline__ int sw2(int x) { return x ^ ((x >> 4) & 1); }

// radix-2 butterfly over register-index bit MM (fully unrolled, constant idx)
#define BFLY(MM)                                              \
    _Pragma("unroll")                                         \
    for (int i_ = 0; i_ < 64; ++i_) {                         \
        if ((i_ & (MM)) == 0) {                               \
            float a_ = v[i_], b_ = v[i_ | (MM)];              \
            v[i_] = a_ + b_;                                  \
            v[i_ | (MM)] = a_ - b_;                           \
        }                                                     \
    }

// launch_bounds 2nd arg = 2: under CUDA-style interpretation (blocks/CU) ->
// 2 blocks * 8 waves = 16 waves/CU -> 128-VGPR cap; under HIP waves/EU
// interpretation -> 256 cap. Either way no forced spill (R2's (512,4) was
// read as 4 blocks/CU -> 64-VGPR cap -> 26 MB of scratch spill traffic).
__global__ __launch_bounds__(512, 2)
void fwht_apply_kernel(const float* __restrict__ z,
                       const float* __restrict__ d1,
                       const float* __restrict__ d2,
                       const float* __restrict__ d3,
                       const float* __restrict__ bvec,
                       const float* __restrict__ sldj_in,
                       float* __restrict__ out) {
    __shared__ float lds[1024 * TT];            // 64 KiB
    const int tid = threadIdx.x;

    if (blockIdx.x == 1024) {                   // ---- sldj block ----
        float acc = 0.0f;
        for (int i = tid; i < D_DIM; i += 512)
            acc += logf(fabsf(d1[i])) + logf(fabsf(d2[i])) + logf(fabsf(d3[i]));
        lds[tid] = acc;
        __syncthreads();
        #pragma unroll
        for (int sft = 256; sft > 0; sft >>= 1) {
            if (tid < sft) lds[tid] += lds[tid + sft];
            __syncthreads();
        }
        if (tid < 128)
            out[(size_t)4 * 32 * 2048 * 128 + tid] = sldj_in[tid] + lds[0];
        return;
    }

    const int r   = tid >> 4;                   // 5-bit "rest" coordinate (0..31)
    const int tt  = tid & 15;                   // t within tile (0..15)
    const int bid = blockIdx.x;
    const int km  = bid >> 3;                   // (k,m) slab (128 total)
    const int t0  = (bid & 7) << 4;             // t-tile base (8 tiles of 16)
    const float s = 0.022097086912079608f;      // 1/sqrt(2048), one per H

    const float* zslab = z + ((size_t)km << 18) + t0;
    const int wid  = tid >> 6;                  // wave id (0..7)
    const int lane = tid & 63;
    const int q    = lane >> 2;                 // row within 16-row run
    const int c    = lane & 3;                  // float4 slot within 64B row

    float v[64];

    // ---- staged load: two 64KiB rounds partitioned by e-bit4 (in P1's rest).
    // Global: dwordx4, 16 rows x 64B fully-used per wave-instruction.
    // LDS layout: row e' = (e&15)|((e>>5)<<4), word = e'*16 + t.  b128 writes.
    #pragma unroll
    for (int h = 0; h < 2; ++h) {
        #pragma unroll
        for (int i = 0; i < 8; ++i) {
            const int n = (wid << 3) | i;                 // run index (0..63)
            const int e = (n << 5) | (h << 4) | q;
            float4 tmp = *(const float4*)(zslab + (size_t)e * T_DIM + (c << 2));
            ((float4*)lds)[(n << 6) + (q << 2) + c] = tmp;
        }
        __syncthreads();
        if (((r >> 4) & 1) == h) {
            // P1 pattern read: word = (r&15)*16 + j*256 + tt.
            // bank = (16*(r&1) + tt) & 31 -> 2-way aliasing (free).
            #pragma unroll
            for (int j = 0; j < 64; ++j) {
                const int e = (j << 5) | r;
                v[j] = lds[(((r & 15) | (j << 4)) << 4) + tt] * (d1[e] * s);
            }
        }
        __syncthreads();
    }

    // ---- P1: e = (j<<5)|r.  F1 on e-bits 5..10 ----
    BFLY(1) BFLY(2) BFLY(4) BFLY(8) BFLY(16) BFLY(32)

    // ---- T1: partition e-bit10 (= j5 on both sides). e' = e & 1023 ----
    #pragma unroll
    for (int j = 0; j < 32; ++j)                      // round A write (e10=0)
        lds[sw1((j << 5) | r) * TT + tt] = v[j];
    __syncthreads();
    #pragma unroll
    for (int j = 0; j < 32; ++j)                      // round A read: P2 map
        v[j] = lds[sw1(j | (r << 5)) * TT + tt];
    __syncthreads();
    #pragma unroll
    for (int j = 32; j < 64; ++j)                     // round B write (e10=1)
        lds[sw1(((j & 31) << 5) | r) * TT + tt] = v[j];
    __syncthreads();
    #pragma unroll
    for (int j = 32; j < 64; ++j)                     // round B read
        v[j] = lds[sw1((j & 31) | (r << 5)) * TT + tt];
    __syncthreads();

    // ---- P2: e = (j&31) | ((j>>5)<<10) | (r<<5) ----
    BFLY(1) BFLY(2) BFLY(4) BFLY(8) BFLY(16)          // F1 e-bits 0..4 (F1 done)
    {   // * d2 * s : per-thread e is two contiguous runs of 32 -> float4
        const float4* q0 = (const float4*)(d2 + (r << 5));
        const float4* q1 = (const float4*)(d2 + 1024 + (r << 5));
        #pragma unroll
        for (int qq = 0; qq < 8; ++qq) {
            float4 a = q0[qq];
            v[4*qq+0] *= a.x * s; v[4*qq+1] *= a.y * s;
            v[4*qq+2] *= a.z * s; v[4*qq+3] *= a.w * s;
            float4 cc = q1[qq];
            v[32+4*qq+0] *= cc.x * s; v[32+4*qq+1] *= cc.y * s;
            v[32+4*qq+2] *= cc.z * s; v[32+4*qq+3] *= cc.w * s;
        }
    }
    BFLY(1) BFLY(2) BFLY(4) BFLY(8) BFLY(16) BFLY(32) // F2 e-bits 0..4,10

    // ---- T2: partition e-bit0 (= j0 on both sides). e' = e >> 1 ----
    #pragma unroll
    for (int j = 0; j < 64; j += 2)                   // round A write (e0=0)
        lds[sw2(((j >> 1) & 15) | (r << 4) | ((j >> 5) << 9)) * TT + tt] = v[j];
    __syncthreads();
    #pragma unroll
    for (int j = 0; j < 64; j += 2)                   // round A read: P3 map
        v[j] = lds[sw2((((j >> 1) & 31) << 4) | (r & 15) | ((r >> 4) << 9)) * TT + tt];
    __syncthreads();
    #pragma unroll
    for (int j = 1; j < 64; j += 2)                   // round B write (e0=1)
        lds[sw2(((j >> 1) & 15) | (r << 4) | ((j >> 5) << 9)) * TT + tt] = v[j];
    __syncthreads();
    #pragma unroll
    for (int j = 1; j < 64; j += 2)                   // round B read
        v[j] = lds[sw2((((j >> 1) & 31) << 4) | (r & 15) | ((r >> 4) << 9)) * TT + tt];
    __syncthreads();

    // ---- P3: e = ((j>>1)<<5) | (j&1) | eRest, eRest = ((r&15)<<1)|((r>>4)<<10)
    BFLY(2) BFLY(4) BFLY(8) BFLY(16) BFLY(32)         // F2 e-bits 5..9 (F2 done)
    {   // * d3 * s : (v[2m], v[2m+1]) sit at (e, e+1) -> float2
        const int eRest = ((r & 15) << 1) | ((r >> 4) << 10);
        #pragma unroll
        for (int m = 0; m < 32; ++m) {
            float2 a = *(const float2*)(d3 + ((m << 5) | eRest));
            v[2*m]   *= a.x * s;
            v[2*m+1] *= a.y * s;
        }
    }
    BFLY(2) BFLY(4) BFLY(8) BFLY(16) BFLY(32) BFLY(1) // F3 e-bits 5..9, 0

    // ---- T3: partition e-bit0 (= j0 on both sides). e' = e >> 1 ----
    #pragma unroll
    for (int j = 0; j < 64; j += 2)                   // round A write (e0=0)
        lds[sw2((((j >> 1) & 31) << 4) | (r & 15) | ((r >> 4) << 9)) * TT + tt] = v[j];
    __syncthreads();
    #pragma unroll
    for (int j = 0; j < 64; j += 2)                   // round A read: P4(=P2) map
        v[j] = lds[sw2(((j >> 1) & 15) | (r << 4) | ((j >> 5) << 9)) * TT + tt];
    __syncthreads();
    #pragma unroll
    for (int j = 1; j < 64; j += 2)                   // round B write (e0=1)
        lds[sw2((((j >> 1) & 31) << 4) | (r & 15) | ((r >> 4) << 9)) * TT + tt] = v[j];
    __syncthreads();
    #pragma unroll
    for (int j = 1; j < 64; j += 2)                   // round B read
        v[j] = lds[sw2(((j >> 1) & 15) | (r << 4) | ((j >> 5) << 9)) * TT + tt];

    // ---- P4: e = (j&31) | ((j>>5)<<10) | (r<<5). F3 e-bits 1..4, 10 ----
    BFLY(2) BFLY(4) BFLY(8) BFLY(16) BFLY(32)         // F3 done

    float* ob = out + ((size_t)km << 18) + t0 + tt;
    {   // + b, store.  b is two contiguous runs of 32 -> float4
        const float4* q0 = (const float4*)(bvec + (r << 5));
        const float4* q1 = (const float4*)(bvec + 1024 + (r << 5));
        #pragma unroll
        for (int qq = 0; qq < 8; ++qq) {
            float4 a = q0[qq];
            const int e0 = (r << 5) + 4*qq;
            ob[(size_t)(e0+0) * T_DIM] = v[4*qq+0] + a.x;
            ob[(size_t)(e0+1) * T_DIM] = v[4*qq+1] + a.y;
            ob[(size_t)(e0+2) * T_DIM] = v[4*qq+2] + a.z;
            ob[(size_t)(e0+3) * T_DIM] = v[4*qq+3] + a.w;
            float4 cc = q1[qq];
            const int e1 = 1024 + (r << 5) + 4*qq;
            ob[(size_t)(e1+0) * T_DIM] = v[32+4*qq+0] + cc.x;
            ob[(size_t)(e1+1) * T_DIM] = v[32+4*qq+1] + cc.y;
            ob[(size_t)(e1+2) * T_DIM] = v[32+4*qq+2] + cc.z;
            ob[(size_t)(e1+3) * T_DIM] = v[32+4*qq+3] + cc.w;
        }
    }
}

extern "C" void kernel_launch(void* const* d_in, const int* in_sizes, int n_in,
                              void* d_out, int out_size, void* d_ws, size_t ws_size,
                              hipStream_t stream) {
    const float* z    = (const float*)d_in[0];
    const float* d1   = (const float*)d_in[1];
    const float* d2   = (const float*)d_in[2];
    const float* d3   = (const float*)d_in[3];
    const float* bvec = (const float*)d_in[4];
    const float* sldj = (const float*)d_in[5];
    float* out = (float*)d_out;

    // blocks 0..1023: FWHT apply (128 slabs x 8 t-tiles); block 1024: sldj
    fwht_apply_kernel<<<1025, 512, 0, stream>>>(z, d1, d2, d3, bvec, sldj, out);
}